// Round 1
// baseline (190.067 us; speedup 1.0000x reference)
//
#include <hip/hip_runtime.h>
#include <cstdint>
#include <cstddef>

#define BATCH 2
#define NVIEW 6
#define MTOK  1369
#define DIM   384
#define VOXPB 65536
#define PFEAT 64
#define HID   256
#define OUTD  16
#define GRIDN 37

typedef float  f32x4  __attribute__((ext_vector_type(4)));
typedef short  bf16x8 __attribute__((ext_vector_type(8)));
typedef _Float16 f16x4 __attribute__((ext_vector_type(4)));

// ---- workspace layout (bytes) ----
#define OFF_MEAN 0
#define SZ_MEAN  (BATCH*MTOK*DIM*2)          // 2,102,784  mean tokens bf16
#define OFF_T    (OFF_MEAN + SZ_MEAN)
#define SZ_T     (BATCH*MTOK*HID*2)          // 1,401,856  T = b1 + mean@W1b, bf16
#define OFF_W1B  (OFF_T + SZ_T)
#define SZ_W1B   (DIM*HID*2)                 // 196,608    W1b B-frags bf16
#define OFF_W1A  (OFF_W1B + SZ_W1B)
#define SZ_W1A   (PFEAT*HID*2)               // 32,768     W1a B-frags bf16
#define OFF_W2T  (OFF_W1A + SZ_W1A)
#define SZ_W2T   (HID*OUTD*2)                // 8,192      W2^T A-frags f16

__device__ __forceinline__ unsigned short f2bf(float x) {
    unsigned u = __float_as_uint(x);
    unsigned r = (u + 0x7FFFu + ((u >> 16) & 1u)) >> 16;   // RNE to bf16
    return (unsigned short)r;
}
__device__ __forceinline__ float bf2f(unsigned short b) {
    return __uint_as_float(((unsigned)b) << 16);
}

// ============================================================================
// Kernel 1: view-mean -> bf16  +  weight fragment pre-swizzle (grid-split)
// ============================================================================
#define MEAN_PAIRS (BATCH*MTOK*DIM/2)        // 525,696
#define MEAN_BLKS  ((MEAN_PAIRS + 255)/256)  // 2054
#define W1B_BLKS   384                       // 98,304 elems
#define W1A_BLKS   64                        // 16,384 elems
#define W2T_BLKS   16                        // 4,096 elems

__global__ __launch_bounds__(256) void prep_kernel(
    const float* __restrict__ patch, const float* __restrict__ W1,
    const float* __restrict__ W2, unsigned short* __restrict__ ws16)
{
    int blk = blockIdx.x;
    if (blk < MEAN_BLKS) {
        int e = blk*256 + threadIdx.x;
        if (e < MEAN_PAIRS) {
            int row = e / (DIM/2);           // b*MTOK + m
            int d2  = e - row*(DIM/2);
            int b = row / MTOK, m = row - b*MTOK;
            const float* p = patch + (((size_t)(b*NVIEW))*MTOK + m)*DIM + d2*2;
            float s0 = 0.f, s1 = 0.f;
            #pragma unroll
            for (int nv = 0; nv < NVIEW; nv++) {
                const float2 v = *(const float2*)(p + (size_t)nv*MTOK*DIM);
                s0 += v.x; s1 += v.y;
            }
            s0 *= (1.0f/6.0f); s1 *= (1.0f/6.0f);
            unsigned short* dst = ws16 + (OFF_MEAN/2) + (size_t)row*DIM + d2*2;
            dst[0] = f2bf(s0); dst[1] = f2bf(s1);
        }
        return;
    }
    blk -= MEAN_BLKS;
    if (blk < W1B_BLKS) {   // B-frag for 16x16x32: B[k][n], n=lane&15, k=(lane>>4)*8+j
        int e = blk*256 + threadIdx.x;
        int j = e & 7, lane = (e >> 3) & 63, nt = (e >> 9) & 15, kc = e >> 13; // kc 0..11
        int k = kc*32 + (lane >> 4)*8 + j;
        int n = nt*16 + (lane & 15);
        ws16[OFF_W1B/2 + e] = f2bf(W1[(PFEAT + k)*HID + n]);
        return;
    }
    blk -= W1B_BLKS;
    if (blk < W1A_BLKS) {
        int e = blk*256 + threadIdx.x;
        int j = e & 7, lane = (e >> 3) & 63, nt = (e >> 9) & 15, kc = e >> 13; // kc 0..1
        int k = kc*32 + (lane >> 4)*8 + j;
        int n = nt*16 + (lane & 15);
        ws16[OFF_W1A/2 + e] = f2bf(W1[k*HID + n]);
        return;
    }
    blk -= W1A_BLKS;
    {   // W2^T A-frags for 16x16x16 f16: A[m=lane&15][k=(lane>>4)*4+j], k global += nt*16
        int e = blk*256 + threadIdx.x;   // 16 blocks * 256 = 4096 exactly
        int j = e & 3, lane = (e >> 2) & 63, nt = e >> 8;
        int k = nt*16 + (lane >> 4)*4 + j;
        _Float16 v = (_Float16)W2[k*OUTD + (lane & 15)];
        ws16[OFF_W2T/2 + e] = __builtin_bit_cast(unsigned short, v);
    }
}

// ============================================================================
// Kernel 2: T[2738][256] = b1 + meanTok @ W1b   (bf16 MFMA, M-tile 64)
// ============================================================================
#define T_ROWS (BATCH*MTOK)                  // 2738
#define T_BLKS ((T_ROWS + 63)/64)            // 43
#define APAD   392                           // 384 + 8 bf16: breaks bank aliasing

__global__ __launch_bounds__(256) void t_gemm_kernel(
    const unsigned short* __restrict__ ws16r, const float* __restrict__ b1,
    unsigned short* __restrict__ ws16)
{
    __shared__ unsigned short Abuf[64*APAD];         // 50,176 B
    const int tid = threadIdx.x;
    const int tileBase = blockIdx.x*64;

    const uint4* msrc = (const uint4*)(ws16r + OFF_MEAN/2);
    uint4* sA = (uint4*)Abuf;
    for (int i = tid; i < 64*48; i += 256) {         // 48 uint4 per 384-bf16 row
        int row = i / 48, c = i - row*48;
        int gr = tileBase + row;
        uint4 v = make_uint4(0,0,0,0);
        if (gr < T_ROWS) v = msrc[(size_t)gr*48 + c];
        sA[row*(APAD/8) + c] = v;                    // APAD/8 = 49 uint4 per row
    }
    __syncthreads();

    const int lane = tid & 63, wv = tid >> 6;
    const int q = lane >> 4, l = lane & 15;
    const uint4* bfr = (const uint4*)(ws16r + OFF_W1B/2);

    f32x4 acc[4][4];                                 // [nt-local][mt]
    #pragma unroll
    for (int a = 0; a < 4; a++)
        #pragma unroll
        for (int m = 0; m < 4; m++) acc[a][m] = (f32x4){0.f,0.f,0.f,0.f};

    for (int kc = 0; kc < 12; kc++) {
        bf16x8 bfrag[4];
        #pragma unroll
        for (int ntl = 0; ntl < 4; ntl++) {
            int nt = wv*4 + ntl;
            bfrag[ntl] = __builtin_bit_cast(bf16x8, bfr[(kc*16 + nt)*64 + lane]);
        }
        #pragma unroll
        for (int mt = 0; mt < 4; mt++) {
            const bf16x8 af = *(const bf16x8*)(Abuf + (mt*16 + l)*APAD + kc*32 + q*8);
            #pragma unroll
            for (int ntl = 0; ntl < 4; ntl++)
                acc[ntl][mt] = __builtin_amdgcn_mfma_f32_16x16x32_bf16(
                                   af, bfrag[ntl], acc[ntl][mt], 0, 0, 0);
        }
    }

    unsigned short* T = ws16 + OFF_T/2;
    #pragma unroll
    for (int ntl = 0; ntl < 4; ntl++) {
        int nt = wv*4 + ntl;
        float bb = b1[nt*16 + l];
        #pragma unroll
        for (int mt = 0; mt < 4; mt++)
            #pragma unroll
            for (int r = 0; r < 4; r++) {
                int row = tileBase + mt*16 + q*4 + r;   // D: row=(lane>>4)*4+reg
                if (row < T_ROWS)
                    T[(size_t)row*HID + nt*16 + l] = f2bf(acc[ntl][mt][r] + bb);
            }
    }
}

// ============================================================================
// Kernel 3: projection + FC1(MFMA bf16) + T-gather + relu + MFMA-transpose
//           + FC2(MFMA f16) ; 512 blocks x 256 thr, 64 voxels/wave
// ============================================================================
__device__ __forceinline__ int proj_idx(float x, float y, float z,
                                        const float* __restrict__ Km,
                                        const float* __restrict__ Rt)
{
    // exact f32, no FMA contraction, numpy op order
    float c0 = __fadd_rn(__fadd_rn(__fadd_rn(__fmul_rn(Rt[0],x), __fmul_rn(Rt[1],y)), __fmul_rn(Rt[2],z)), Rt[3]);
    float c1 = __fadd_rn(__fadd_rn(__fadd_rn(__fmul_rn(Rt[4],x), __fmul_rn(Rt[5],y)), __fmul_rn(Rt[6],z)), Rt[7]);
    float c2 = __fadd_rn(__fadd_rn(__fadd_rn(__fmul_rn(Rt[8],x), __fmul_rn(Rt[9],y)), __fmul_rn(Rt[10],z)), Rt[11]);
    float p0 = __fadd_rn(__fadd_rn(__fmul_rn(Km[0],c0), __fmul_rn(Km[1],c1)), __fmul_rn(Km[2],c2));
    float p1 = __fadd_rn(__fadd_rn(__fmul_rn(Km[3],c0), __fmul_rn(Km[4],c1)), __fmul_rn(Km[5],c2));
    float p2 = __fadd_rn(__fadd_rn(__fmul_rn(Km[6],c0), __fmul_rn(Km[7],c1)), __fmul_rn(Km[8],c2));
    float zz = __fadd_rn(p2, 1e-6f);
    float u  = __fmul_rn(__fdiv_rn(p0, zz), 518.0f/600.0f);
    float v  = __fmul_rn(__fdiv_rn(p1, zz), 518.0f/900.0f);
    float fu = __fdiv_rn(u, 14.0f);
    float fv = __fdiv_rn(v, 14.0f);
    // numpy/x86 cvttss2si: overflow & NaN -> INT_MIN (then clamp to 0)
    int px = (__builtin_fabsf(fu) < 2147483648.0f) ? (int)fu : (int)0x80000000;
    int py = (__builtin_fabsf(fv) < 2147483648.0f) ? (int)fv : (int)0x80000000;
    px = min(max(px, 0), GRIDN-1);
    py = min(max(py, 0), GRIDN-1);
    return px*GRIDN + py;
}

__global__ __launch_bounds__(256) void main_kernel(
    const float* __restrict__ vf, const float* __restrict__ coords,
    const float* __restrict__ Km, const float* __restrict__ Rt,
    const unsigned short* __restrict__ ws16, const float* __restrict__ b2,
    float* __restrict__ out)
{
    __shared__ uint4 w1aS[2048];     // W1a B-frags, 32 KB
    __shared__ int   idxS[256];

    const int tid = threadIdx.x;
    const uint4* w1aG = (const uint4*)(ws16 + OFF_W1A/2);
    for (int i = tid; i < 2048; i += 256) w1aS[i] = w1aG[i];

    {   // per-thread projection for one voxel
        int vox = blockIdx.x*256 + tid;
        const float* cp = coords + (size_t)vox*3;
        idxS[tid] = proj_idx(cp[0], cp[1], cp[2], Km, Rt);
    }
    __syncthreads();

    const int lane = tid & 63, wv = tid >> 6;
    const int q = lane >> 4, l = lane & 15;
    const int voxBase = blockIdx.x*256 + wv*64;
    const int b = blockIdx.x >> 8;                     // 256 blocks per batch

    // A1 fragments: vf rows, f32 -> bf16.  A[m=l][k=q*8+j], kc in {0,1}
    bf16x8 a1[4][2];
    #pragma unroll
    for (int mt = 0; mt < 4; mt++) {
        const float* vp = vf + (size_t)(voxBase + mt*16 + l)*PFEAT;
        #pragma unroll
        for (int kc = 0; kc < 2; kc++) {
            const float* pp = vp + kc*32 + q*8;
            f32x4 v0 = *(const f32x4*)pp;
            f32x4 v1 = *(const f32x4*)(pp + 4);
            bf16x8 f;
            f[0]=f2bf(v0[0]); f[1]=f2bf(v0[1]); f[2]=f2bf(v0[2]); f[3]=f2bf(v0[3]);
            f[4]=f2bf(v1[0]); f[5]=f2bf(v1[1]); f[6]=f2bf(v1[2]); f[7]=f2bf(v1[3]);
            a1[mt][kc] = f;
        }
    }

    // T row offsets for this lane's 16 voxel rows (D-layout rows q*4+r)
    const unsigned short* T = ws16 + OFF_T/2;
    int toff[4][4];
    #pragma unroll
    for (int mt = 0; mt < 4; mt++)
        #pragma unroll
        for (int r = 0; r < 4; r++)
            toff[mt][r] = (b*MTOK + idxS[wv*64 + mt*16 + q*4 + r])*HID;

    // W2^T A-frags -> registers (16 x 8B)
    f16x4 w2t[16];
    #pragma unroll
    for (int nt = 0; nt < 16; nt++)
        w2t[nt] = *(const f16x4*)(ws16 + OFF_W2T/2 + (nt*64 + lane)*4);

    // identity B-frag for the transpose MFMA: B[k=q*4+j][n=l] == (k==n)
    f16x4 ident;
    #pragma unroll
    for (int j = 0; j < 4; j++)
        ident[j] = (q*4 + j == l) ? (_Float16)1.0f : (_Float16)0.0f;

    const f32x4 zero4 = {0.f,0.f,0.f,0.f};
    f32x4 acc2[4] = {zero4, zero4, zero4, zero4};      // out^T: row=o, col=vox

    for (int nt = 0; nt < 16; nt++) {
        bf16x8 wf0 = __builtin_bit_cast(bf16x8, w1aS[nt*64 + lane]);
        bf16x8 wf1 = __builtin_bit_cast(bf16x8, w1aS[(16 + nt)*64 + lane]);
        #pragma unroll
        for (int mt = 0; mt < 4; mt++) {
            f32x4 d1 = __builtin_amdgcn_mfma_f32_16x16x32_bf16(a1[mt][0], wf0, zero4, 0, 0, 0);
            d1       = __builtin_amdgcn_mfma_f32_16x16x32_bf16(a1[mt][1], wf1, d1,    0, 0, 0);
            // h = relu(d1 + T[idx])  (lane holds h[row=q*4+r][col=nt*16+l])
            f16x4 aT;
            #pragma unroll
            for (int r = 0; r < 4; r++) {
                float t = bf2f(T[toff[mt][r] + nt*16 + l]);
                float v = d1[r] + t;
                v = fmaxf(v, 0.0f);
                aT[r] = (_Float16)v;
            }
            // MFMA transpose: D = (h-block-as-A) x I  => lane holds h[vox=l][col=q*4+j]
            f32x4 ht = __builtin_amdgcn_mfma_f32_16x16x16f16(aT, ident, zero4, 0, 0, 0);
            f16x4 hb;
            hb[0]=(_Float16)ht[0]; hb[1]=(_Float16)ht[1];
            hb[2]=(_Float16)ht[2]; hb[3]=(_Float16)ht[3];   // exact (values are f16)
            // FC2: out^T += W2^T(A) x h^T(B)
            acc2[mt] = __builtin_amdgcn_mfma_f32_16x16x16f16(w2t[nt], hb, acc2[mt], 0, 0, 0);
        }
    }

    // epilogue: lane l = voxel, rows q*4+r = output channel
    f32x4 bb = *(const f32x4*)(b2 + q*4);
    #pragma unroll
    for (int mt = 0; mt < 4; mt++) {
        f32x4 o = acc2[mt] + bb;
        *(f32x4*)(out + (size_t)(voxBase + mt*16 + l)*OUTD + q*4) = o;
    }
}

// ============================================================================
extern "C" void kernel_launch(void* const* d_in, const int* in_sizes, int n_in,
                              void* d_out, int out_size, void* d_ws, size_t ws_size,
                              hipStream_t stream)
{
    const float* patch  = (const float*)d_in[0];
    const float* vfeat  = (const float*)d_in[1];
    const float* coords = (const float*)d_in[2];
    const float* Km     = (const float*)d_in[3];
    const float* Rt     = (const float*)d_in[4];
    const float* W1     = (const float*)d_in[5];
    const float* b1     = (const float*)d_in[6];
    const float* W2     = (const float*)d_in[7];
    const float* b2     = (const float*)d_in[8];
    float* out          = (float*)d_out;
    unsigned short* ws16 = (unsigned short*)d_ws;

    const int prepBlocks = MEAN_BLKS + W1B_BLKS + W1A_BLKS + W2T_BLKS; // 2518
    prep_kernel<<<prepBlocks, 256, 0, stream>>>(patch, W1, W2, ws16);
    t_gemm_kernel<<<T_BLKS, 256, 0, stream>>>(ws16, b1, ws16);
    main_kernel<<<(BATCH*VOXPB)/256, 256, 0, stream>>>(vfeat, coords, Km, Rt,
                                                       ws16, b2, out);
}

// Round 2
// 127.857 us; speedup vs baseline: 1.4866x; 1.4866x over previous
//
#include <hip/hip_runtime.h>
#include <cstdint>
#include <cstddef>

#define BATCH 2
#define NVIEW 6
#define MTOK  1369
#define DIM   384
#define VOXPB 65536
#define PFEAT 64
#define HID   256
#define OUTD  16
#define GRIDN 37

typedef float  f32x4  __attribute__((ext_vector_type(4)));
typedef short  bf16x8 __attribute__((ext_vector_type(8)));
typedef _Float16 f16x4 __attribute__((ext_vector_type(4)));

// ---- workspace layout (bytes) ----
#define OFF_MEAN 0
#define SZ_MEAN  (BATCH*MTOK*DIM*2)          // mean tokens bf16
#define OFF_T    (OFF_MEAN + SZ_MEAN)
#define SZ_T     (BATCH*MTOK*HID*2)          // T swizzled: T_sw[t][l*16+nt] = T[t][nt*16+l]
#define OFF_W1B  (OFF_T + SZ_T)
#define SZ_W1B   (DIM*HID*2)                 // W1b B-frags bf16
#define OFF_W1A  (OFF_W1B + SZ_W1B)
#define SZ_W1A   (PFEAT*HID*2)               // W1a B-frags bf16
#define OFF_W2T  (OFF_W1A + SZ_W1A)
#define SZ_W2T   (HID*OUTD*2)                // W2^T A-frags f16

__device__ __forceinline__ unsigned short f2bf(float x) {
    unsigned u = __float_as_uint(x);
    unsigned r = (u + 0x7FFFu + ((u >> 16) & 1u)) >> 16;   // RNE to bf16
    return (unsigned short)r;
}

// ============================================================================
// Kernel 1: view-mean -> bf16  +  weight fragment pre-swizzle (grid-split)
// ============================================================================
#define MEAN_PAIRS (BATCH*MTOK*DIM/2)        // 525,696
#define MEAN_BLKS  ((MEAN_PAIRS + 255)/256)  // 2054
#define W1B_BLKS   384
#define W1A_BLKS   64
#define W2T_BLKS   16

__global__ __launch_bounds__(256) void prep_kernel(
    const float* __restrict__ patch, const float* __restrict__ W1,
    const float* __restrict__ W2, unsigned short* __restrict__ ws16)
{
    int blk = blockIdx.x;
    if (blk < MEAN_BLKS) {
        int e = blk*256 + threadIdx.x;
        if (e < MEAN_PAIRS) {
            int row = e / (DIM/2);           // b*MTOK + m
            int d2  = e - row*(DIM/2);
            int b = row / MTOK, m = row - b*MTOK;
            const float* p = patch + (((size_t)(b*NVIEW))*MTOK + m)*DIM + d2*2;
            float s0 = 0.f, s1 = 0.f;
            #pragma unroll
            for (int nv = 0; nv < NVIEW; nv++) {
                const float2 v = *(const float2*)(p + (size_t)nv*MTOK*DIM);
                s0 += v.x; s1 += v.y;
            }
            s0 *= (1.0f/6.0f); s1 *= (1.0f/6.0f);
            unsigned short* dst = ws16 + (OFF_MEAN/2) + (size_t)row*DIM + d2*2;
            dst[0] = f2bf(s0); dst[1] = f2bf(s1);
        }
        return;
    }
    blk -= MEAN_BLKS;
    if (blk < W1B_BLKS) {   // B-frag 16x16x32: n=lane&15, k=(lane>>4)*8+j
        int e = blk*256 + threadIdx.x;
        int j = e & 7, lane = (e >> 3) & 63, nt = (e >> 9) & 15, kc = e >> 13;
        int k = kc*32 + (lane >> 4)*8 + j;
        int n = nt*16 + (lane & 15);
        ws16[OFF_W1B/2 + e] = f2bf(W1[(PFEAT + k)*HID + n]);
        return;
    }
    blk -= W1B_BLKS;
    if (blk < W1A_BLKS) {
        int e = blk*256 + threadIdx.x;
        int j = e & 7, lane = (e >> 3) & 63, nt = (e >> 9) & 15, kc = e >> 13;
        int k = kc*32 + (lane >> 4)*8 + j;
        int n = nt*16 + (lane & 15);
        ws16[OFF_W1A/2 + e] = f2bf(W1[k*HID + n]);
        return;
    }
    blk -= W1A_BLKS;
    {   // W2^T A-frags 16x16x16 f16: A[m=lane&15][k=(lane>>4)*4+j + nt*16]
        int e = blk*256 + threadIdx.x;
        int j = e & 3, lane = (e >> 2) & 63, nt = e >> 8;
        int k = nt*16 + (lane >> 4)*4 + j;
        _Float16 v = (_Float16)W2[k*OUTD + (lane & 15)];
        ws16[OFF_W2T/2 + e] = __builtin_bit_cast(unsigned short, v);
    }
}

// ============================================================================
// Kernel 2: T_sw = swizzle(b1 + meanTok @ W1b)   (bf16 MFMA, M-tile 64)
// ============================================================================
#define T_ROWS (BATCH*MTOK)                  // 2738
#define T_BLKS ((T_ROWS + 63)/64)            // 43
#define APAD   392

__global__ __launch_bounds__(256) void t_gemm_kernel(
    const unsigned short* __restrict__ ws16r, const float* __restrict__ b1,
    unsigned short* __restrict__ ws16)
{
    __shared__ unsigned short Abuf[64*APAD];
    const int tid = threadIdx.x;
    const int tileBase = blockIdx.x*64;

    const uint4* msrc = (const uint4*)(ws16r + OFF_MEAN/2);
    uint4* sA = (uint4*)Abuf;
    for (int i = tid; i < 64*48; i += 256) {
        int row = i / 48, c = i - row*48;
        int gr = tileBase + row;
        uint4 v = make_uint4(0,0,0,0);
        if (gr < T_ROWS) v = msrc[(size_t)gr*48 + c];
        sA[row*(APAD/8) + c] = v;
    }
    __syncthreads();

    const int lane = tid & 63, wv = tid >> 6;
    const int q = lane >> 4, l = lane & 15;
    const uint4* bfr = (const uint4*)(ws16r + OFF_W1B/2);

    f32x4 acc[4][4];
    #pragma unroll
    for (int a = 0; a < 4; a++)
        #pragma unroll
        for (int m = 0; m < 4; m++) acc[a][m] = (f32x4){0.f,0.f,0.f,0.f};

    for (int kc = 0; kc < 12; kc++) {
        bf16x8 bfrag[4];
        #pragma unroll
        for (int ntl = 0; ntl < 4; ntl++) {
            int nt = wv*4 + ntl;
            bfrag[ntl] = __builtin_bit_cast(bf16x8, bfr[(kc*16 + nt)*64 + lane]);
        }
        #pragma unroll
        for (int mt = 0; mt < 4; mt++) {
            const bf16x8 af = *(const bf16x8*)(Abuf + (mt*16 + l)*APAD + kc*32 + q*8);
            #pragma unroll
            for (int ntl = 0; ntl < 4; ntl++)
                acc[ntl][mt] = __builtin_amdgcn_mfma_f32_16x16x32_bf16(
                                   af, bfrag[ntl], acc[ntl][mt], 0, 0, 0);
        }
    }

    // epilogue: swizzled store  T_sw[row][l*16 + nt], nt = wv*4+ntl -> packed b64
    unsigned short* T = ws16 + OFF_T/2;
    float bbv[4];
    #pragma unroll
    for (int ntl = 0; ntl < 4; ntl++) bbv[ntl] = b1[(wv*4 + ntl)*16 + l];
    #pragma unroll
    for (int mt = 0; mt < 4; mt++)
        #pragma unroll
        for (int r = 0; r < 4; r++) {
            int row = tileBase + mt*16 + q*4 + r;       // D: row=(lane>>4)*4+reg
            if (row < T_ROWS) {
                ushort4 pk;
                pk.x = f2bf(acc[0][mt][r] + bbv[0]);
                pk.y = f2bf(acc[1][mt][r] + bbv[1]);
                pk.z = f2bf(acc[2][mt][r] + bbv[2]);
                pk.w = f2bf(acc[3][mt][r] + bbv[3]);
                *(ushort4*)(T + (size_t)row*HID + l*16 + wv*4) = pk;
            }
        }
}

// ============================================================================
// Kernel 3: projection + FC1(MFMA bf16) + reg-resident T + MFMA-transpose
//           + FC2(MFMA f16) ; 1024 blocks x 256 thr, 32 voxels/wave
// ============================================================================
__device__ __forceinline__ int proj_idx(float x, float y, float z,
                                        const float* __restrict__ Km,
                                        const float* __restrict__ Rt)
{
    float c0 = __fadd_rn(__fadd_rn(__fadd_rn(__fmul_rn(Rt[0],x), __fmul_rn(Rt[1],y)), __fmul_rn(Rt[2],z)), Rt[3]);
    float c1 = __fadd_rn(__fadd_rn(__fadd_rn(__fmul_rn(Rt[4],x), __fmul_rn(Rt[5],y)), __fmul_rn(Rt[6],z)), Rt[7]);
    float c2 = __fadd_rn(__fadd_rn(__fadd_rn(__fmul_rn(Rt[8],x), __fmul_rn(Rt[9],y)), __fmul_rn(Rt[10],z)), Rt[11]);
    float p0 = __fadd_rn(__fadd_rn(__fmul_rn(Km[0],c0), __fmul_rn(Km[1],c1)), __fmul_rn(Km[2],c2));
    float p1 = __fadd_rn(__fadd_rn(__fmul_rn(Km[3],c0), __fmul_rn(Km[4],c1)), __fmul_rn(Km[5],c2));
    float p2 = __fadd_rn(__fadd_rn(__fmul_rn(Km[6],c0), __fmul_rn(Km[7],c1)), __fmul_rn(Km[8],c2));
    float zz = __fadd_rn(p2, 1e-6f);
    float u  = __fmul_rn(__fdiv_rn(p0, zz), 518.0f/600.0f);
    float v  = __fmul_rn(__fdiv_rn(p1, zz), 518.0f/900.0f);
    float fu = __fdiv_rn(u, 14.0f);
    float fv = __fdiv_rn(v, 14.0f);
    int px = (__builtin_fabsf(fu) < 2147483648.0f) ? (int)fu : (int)0x80000000;
    int py = (__builtin_fabsf(fv) < 2147483648.0f) ? (int)fv : (int)0x80000000;
    px = min(max(px, 0), GRIDN-1);
    py = min(max(py, 0), GRIDN-1);
    return px*GRIDN + py;
}

__global__ __launch_bounds__(256, 4) void main_kernel(
    const float* __restrict__ vf, const float* __restrict__ coords,
    const float* __restrict__ Km, const float* __restrict__ Rt,
    const unsigned short* __restrict__ ws16, const float* __restrict__ b2,
    float* __restrict__ out)
{
    __shared__ uint4 w1aS[2048];     // 32 KB W1a B-frags
    __shared__ int   idxS[128];

    const int tid = threadIdx.x;
    const uint4* w1aG = (const uint4*)(ws16 + OFF_W1A/2);
    #pragma unroll
    for (int i = 0; i < 8; i++) w1aS[i*256 + tid] = w1aG[i*256 + tid];

    if (tid < 128) {
        int vox = blockIdx.x*128 + tid;
        const float* cp = coords + (size_t)vox*3;
        idxS[tid] = proj_idx(cp[0], cp[1], cp[2], Km, Rt);
    }
    __syncthreads();

    const int lane = tid & 63, wv = tid >> 6;
    const int q = lane >> 4, l = lane & 15;
    const int voxBase = blockIdx.x*128 + wv*32;
    const int b = blockIdx.x >> 9;                 // 512 blocks per batch

    // A1 fragments: vf rows f32 -> bf16.  A[m=l][k=q*8+j], kc in {0,1}
    bf16x8 a1[2][2];
    #pragma unroll
    for (int mt = 0; mt < 2; mt++) {
        const float* vp = vf + (size_t)(voxBase + mt*16 + l)*PFEAT;
        #pragma unroll
        for (int kc = 0; kc < 2; kc++) {
            const float* pp = vp + kc*32 + q*8;
            f32x4 v0 = *(const f32x4*)pp;
            f32x4 v1 = *(const f32x4*)(pp + 4);
            bf16x8 f;
            f[0]=f2bf(v0[0]); f[1]=f2bf(v0[1]); f[2]=f2bf(v0[2]); f[3]=f2bf(v0[3]);
            f[4]=f2bf(v1[0]); f[5]=f2bf(v1[1]); f[6]=f2bf(v1[2]); f[7]=f2bf(v1[3]);
            a1[mt][kc] = f;
        }
    }

    // preload swizzled T rows into regs: 8 rows x 32 B (vector loads, full MLP)
    const unsigned short* T = ws16 + OFF_T/2;
    uint4 tra[2][4][2];
    #pragma unroll
    for (int mt = 0; mt < 2; mt++)
        #pragma unroll
        for (int r = 0; r < 4; r++) {
            int row = b*MTOK + idxS[wv*32 + mt*16 + q*4 + r];
            const uint4* tp = (const uint4*)(T + (size_t)row*HID + l*16);
            tra[mt][r][0] = tp[0];
            tra[mt][r][1] = tp[1];
        }

    const unsigned short* w2tG = ws16 + OFF_W2T/2;

    // identity B-frag for the transpose MFMA
    f16x4 ident;
    #pragma unroll
    for (int j = 0; j < 4; j++)
        ident[j] = (q*4 + j == l) ? (_Float16)1.0f : (_Float16)0.0f;

    const f32x4 zero4 = {0.f,0.f,0.f,0.f};
    f32x4 acc2[2] = {zero4, zero4};

    #pragma unroll
    for (int nt = 0; nt < 16; nt++) {
        bf16x8 wf0 = __builtin_bit_cast(bf16x8, w1aS[nt*64 + lane]);
        bf16x8 wf1 = __builtin_bit_cast(bf16x8, w1aS[(16 + nt)*64 + lane]);
        f16x4 w2t = *(const f16x4*)(w2tG + (nt*64 + lane)*4);  // L2, hoisted by unroll
        #pragma unroll
        for (int mt = 0; mt < 2; mt++) {
            f32x4 d1 = __builtin_amdgcn_mfma_f32_16x16x32_bf16(a1[mt][0], wf0, zero4, 0, 0, 0);
            d1       = __builtin_amdgcn_mfma_f32_16x16x32_bf16(a1[mt][1], wf1, d1,    0, 0, 0);
            f16x4 aT;
            #pragma unroll
            for (int r = 0; r < 4; r++) {
                unsigned dw = ((const unsigned*)&tra[mt][r])[nt >> 1];
                float tval = (nt & 1) ? __uint_as_float(dw & 0xFFFF0000u)
                                      : __uint_as_float(dw << 16);
                float v = fmaxf(d1[r] + tval, 0.0f);
                aT[r] = (_Float16)v;
            }
            // transpose: lane -> h[vox=l][col=q*4+j]
            f32x4 ht = __builtin_amdgcn_mfma_f32_16x16x16f16(aT, ident, zero4, 0, 0, 0);
            f16x4 hb;
            hb[0]=(_Float16)ht[0]; hb[1]=(_Float16)ht[1];
            hb[2]=(_Float16)ht[2]; hb[3]=(_Float16)ht[3];
            acc2[mt] = __builtin_amdgcn_mfma_f32_16x16x16f16(w2t, hb, acc2[mt], 0, 0, 0);
        }
    }

    // epilogue: lane l = voxel, rows q*4+r = output channel
    f32x4 bb = *(const f32x4*)(b2 + q*4);
    #pragma unroll
    for (int mt = 0; mt < 2; mt++) {
        f32x4 o = acc2[mt] + bb;
        *(f32x4*)(out + (size_t)(voxBase + mt*16 + l)*OUTD + q*4) = o;
    }
}

// ============================================================================
extern "C" void kernel_launch(void* const* d_in, const int* in_sizes, int n_in,
                              void* d_out, int out_size, void* d_ws, size_t ws_size,
                              hipStream_t stream)
{
    const float* patch  = (const float*)d_in[0];
    const float* vfeat  = (const float*)d_in[1];
    const float* coords = (const float*)d_in[2];
    const float* Km     = (const float*)d_in[3];
    const float* Rt     = (const float*)d_in[4];
    const float* W1     = (const float*)d_in[5];
    const float* b1     = (const float*)d_in[6];
    const float* W2     = (const float*)d_in[7];
    const float* b2     = (const float*)d_in[8];
    float* out          = (float*)d_out;
    unsigned short* ws16 = (unsigned short*)d_ws;

    const int prepBlocks = MEAN_BLKS + W1B_BLKS + W1A_BLKS + W2T_BLKS; // 2518
    prep_kernel<<<prepBlocks, 256, 0, stream>>>(patch, W1, W2, ws16);
    t_gemm_kernel<<<T_BLKS, 256, 0, stream>>>(ws16, b1, ws16);
    main_kernel<<<(BATCH*VOXPB)/128, 256, 0, stream>>>(vfeat, coords, Km, Rt,
                                                       ws16, b2, out);
}

// Round 3
// 121.124 us; speedup vs baseline: 1.5692x; 1.0556x over previous
//
#include <hip/hip_runtime.h>
#include <cstdint>
#include <cstddef>

#define BATCH 2
#define NVIEW 6
#define MTOK  1369
#define DIM   384
#define VOXPB 65536
#define PFEAT 64
#define HID   256
#define OUTD  16
#define GRIDN 37

typedef float  f32x4  __attribute__((ext_vector_type(4)));
typedef short  bf16x8 __attribute__((ext_vector_type(8)));
typedef _Float16 f16x4 __attribute__((ext_vector_type(4)));

// ---- workspace layout (bytes) ----
#define OFF_T    0
#define SZ_T     (BATCH*MTOK*HID*2)          // T swizzled: T_sw[t][l*16+nt] = T[t][nt*16+l]
#define OFF_W1B  (OFF_T + SZ_T)
#define SZ_W1B   (DIM*HID*2)                 // W1b B-frags bf16
#define OFF_W1A  (OFF_W1B + SZ_W1B)
#define SZ_W1A   (PFEAT*HID*2)               // W1a B-frags bf16
#define OFF_W2T  (OFF_W1A + SZ_W1A)
#define SZ_W2T   (HID*OUTD*2)                // W2^T A-frags f16

__device__ __forceinline__ unsigned short f2bf(float x) {
    unsigned u = __float_as_uint(x);
    unsigned r = (u + 0x7FFFu + ((u >> 16) & 1u)) >> 16;   // RNE to bf16
    return (unsigned short)r;
}

// ============================================================================
// Kernel 1: weight fragment pre-swizzle only (mean is fused into t_gemm now)
// ============================================================================
#define W1B_BLKS   384
#define W1A_BLKS   64
#define W2T_BLKS   16

__global__ __launch_bounds__(256) void prep_kernel(
    const float* __restrict__ W1, const float* __restrict__ W2,
    unsigned short* __restrict__ ws16)
{
    int blk = blockIdx.x;
    if (blk < W1B_BLKS) {   // B-frag 16x16x32: n=lane&15, k=(lane>>4)*8+j
        int e = blk*256 + threadIdx.x;
        int j = e & 7, lane = (e >> 3) & 63, nt = (e >> 9) & 15, kc = e >> 13;
        int k = kc*32 + (lane >> 4)*8 + j;
        int n = nt*16 + (lane & 15);
        ws16[OFF_W1B/2 + e] = f2bf(W1[(PFEAT + k)*HID + n]);
        return;
    }
    blk -= W1B_BLKS;
    if (blk < W1A_BLKS) {
        int e = blk*256 + threadIdx.x;
        int j = e & 7, lane = (e >> 3) & 63, nt = (e >> 9) & 15, kc = e >> 13;
        int k = kc*32 + (lane >> 4)*8 + j;
        int n = nt*16 + (lane & 15);
        ws16[OFF_W1A/2 + e] = f2bf(W1[k*HID + n]);
        return;
    }
    blk -= W1A_BLKS;
    {   // W2^T A-frags 16x16x16 f16: A[m=lane&15][k=(lane>>4)*4+j + nt*16]
        int e = blk*256 + threadIdx.x;
        int j = e & 3, lane = (e >> 2) & 63, nt = e >> 8;
        int k = nt*16 + (lane >> 4)*4 + j;
        _Float16 v = (_Float16)W2[k*OUTD + (lane & 15)];
        ws16[OFF_W2T/2 + e] = __builtin_bit_cast(unsigned short, v);
    }
}

// ============================================================================
// Kernel 2: T_sw = swizzle(b1 + mean_views(patch) @ W1b)
//           fused 6-view mean in A-staging; M-tile 16 -> 172 blocks
// ============================================================================
#define T_ROWS (BATCH*MTOK)                  // 2738
#define TM     16
#define T_BLKS ((T_ROWS + TM - 1)/TM)        // 172
#define APAD   392

__global__ __launch_bounds__(256) void t_gemm_kernel(
    const float* __restrict__ patch, const unsigned short* __restrict__ ws16r,
    const float* __restrict__ b1, unsigned short* __restrict__ ws16)
{
    __shared__ unsigned short Abuf[TM*APAD];   // 12,544 B
    const int tid = threadIdx.x;
    const int tileBase = blockIdx.x*TM;

    // stage: 16 rows x 96 float4-cols, 6-view mean -> bf16
    #pragma unroll
    for (int it = 0; it < 6; it++) {
        int i = it*256 + tid;                  // < 1536
        int row = i / 96, c = i - row*96;
        int gr = tileBase + row;
        f32x4 s = {0.f,0.f,0.f,0.f};
        if (gr < T_ROWS) {
            int b = (gr >= MTOK) ? 1 : 0;
            int m = gr - b*MTOK;
            const float* p = patch + (((size_t)(b*NVIEW))*MTOK + m)*DIM + c*4;
            #pragma unroll
            for (int nv = 0; nv < NVIEW; nv++)
                s += *(const f32x4*)(p + (size_t)nv*MTOK*DIM);
            s *= (1.0f/6.0f);
        }
        ushort4 pk;
        pk.x = f2bf(s[0]); pk.y = f2bf(s[1]); pk.z = f2bf(s[2]); pk.w = f2bf(s[3]);
        *(ushort4*)(Abuf + row*APAD + c*4) = pk;
    }
    __syncthreads();

    const int lane = tid & 63, wv = tid >> 6;
    const int q = lane >> 4, l = lane & 15;
    const uint4* bfr = (const uint4*)(ws16r + OFF_W1B/2);

    f32x4 acc[4];                              // 4 N-tiles per wave (nt = wv*4+ntl)
    #pragma unroll
    for (int a = 0; a < 4; a++) acc[a] = (f32x4){0.f,0.f,0.f,0.f};

    for (int kc = 0; kc < 12; kc++) {
        const bf16x8 af = *(const bf16x8*)(Abuf + l*APAD + kc*32 + q*8);
        #pragma unroll
        for (int ntl = 0; ntl < 4; ntl++) {
            bf16x8 bfrag = __builtin_bit_cast(bf16x8, bfr[(kc*16 + wv*4 + ntl)*64 + lane]);
            acc[ntl] = __builtin_amdgcn_mfma_f32_16x16x32_bf16(af, bfrag, acc[ntl], 0, 0, 0);
        }
    }

    // epilogue: T_sw[row][l*16 + wv*4 + ntl]  (D: row = q*4+reg, col = l)
    unsigned short* T = ws16 + OFF_T/2;
    float bbv[4];
    #pragma unroll
    for (int ntl = 0; ntl < 4; ntl++) bbv[ntl] = b1[(wv*4 + ntl)*16 + l];
    #pragma unroll
    for (int r = 0; r < 4; r++) {
        int row = tileBase + q*4 + r;
        if (row < T_ROWS) {
            ushort4 pk;
            pk.x = f2bf(acc[0][r] + bbv[0]);
            pk.y = f2bf(acc[1][r] + bbv[1]);
            pk.z = f2bf(acc[2][r] + bbv[2]);
            pk.w = f2bf(acc[3][r] + bbv[3]);
            *(ushort4*)(T + (size_t)row*HID + l*16 + wv*4) = pk;
        }
    }
}

// ============================================================================
// Kernel 3: projection + FC1(MFMA bf16) + reg-resident T + MFMA-transpose
//           + FC2(MFMA f16) ; 2048 blocks x 256 thr, 16 voxels/wave
// ============================================================================
__device__ __forceinline__ int proj_idx(float x, float y, float z,
                                        const float* __restrict__ Km,
                                        const float* __restrict__ Rt)
{
    float c0 = __fadd_rn(__fadd_rn(__fadd_rn(__fmul_rn(Rt[0],x), __fmul_rn(Rt[1],y)), __fmul_rn(Rt[2],z)), Rt[3]);
    float c1 = __fadd_rn(__fadd_rn(__fadd_rn(__fmul_rn(Rt[4],x), __fmul_rn(Rt[5],y)), __fmul_rn(Rt[6],z)), Rt[7]);
    float c2 = __fadd_rn(__fadd_rn(__fadd_rn(__fmul_rn(Rt[8],x), __fmul_rn(Rt[9],y)), __fmul_rn(Rt[10],z)), Rt[11]);
    float p0 = __fadd_rn(__fadd_rn(__fmul_rn(Km[0],c0), __fmul_rn(Km[1],c1)), __fmul_rn(Km[2],c2));
    float p1 = __fadd_rn(__fadd_rn(__fmul_rn(Km[3],c0), __fmul_rn(Km[4],c1)), __fmul_rn(Km[5],c2));
    float p2 = __fadd_rn(__fadd_rn(__fmul_rn(Km[6],c0), __fmul_rn(Km[7],c1)), __fmul_rn(Km[8],c2));
    float zz = __fadd_rn(p2, 1e-6f);
    float u  = __fmul_rn(__fdiv_rn(p0, zz), 518.0f/600.0f);
    float v  = __fmul_rn(__fdiv_rn(p1, zz), 518.0f/900.0f);
    float fu = __fdiv_rn(u, 14.0f);
    float fv = __fdiv_rn(v, 14.0f);
    int px = (__builtin_fabsf(fu) < 2147483648.0f) ? (int)fu : (int)0x80000000;
    int py = (__builtin_fabsf(fv) < 2147483648.0f) ? (int)fv : (int)0x80000000;
    px = min(max(px, 0), GRIDN-1);
    py = min(max(py, 0), GRIDN-1);
    return px*GRIDN + py;
}

__global__ __launch_bounds__(256, 4) void main_kernel(
    const float* __restrict__ vf, const float* __restrict__ coords,
    const float* __restrict__ Km, const float* __restrict__ Rt,
    const unsigned short* __restrict__ ws16, const float* __restrict__ b2,
    float* __restrict__ out)
{
    __shared__ uint4 w1aS[2048];     // 32 KB W1a B-frags
    __shared__ int   idxS[64];

    const int tid = threadIdx.x;
    const uint4* w1aG = (const uint4*)(ws16 + OFF_W1A/2);
    #pragma unroll
    for (int i = 0; i < 8; i++) w1aS[i*256 + tid] = w1aG[i*256 + tid];

    if (tid < 64) {
        int vox = blockIdx.x*64 + tid;
        const float* cp = coords + (size_t)vox*3;
        idxS[tid] = proj_idx(cp[0], cp[1], cp[2], Km, Rt);
    }
    __syncthreads();

    const int lane = tid & 63, wv = tid >> 6;
    const int q = lane >> 4, l = lane & 15;
    const int voxG = blockIdx.x*64 + wv*16;        // 16 voxels per wave
    const int b = blockIdx.x >> 10;                // 1024 blocks per batch

    // A1 fragments: vf row (voxG+l), f32 -> bf16.  A[m=l][k=q*8+j], kc in {0,1}
    bf16x8 a1[2];
    {
        const float* vp = vf + (size_t)(voxG + l)*PFEAT;
        #pragma unroll
        for (int kc = 0; kc < 2; kc++) {
            const float* pp = vp + kc*32 + q*8;
            f32x4 v0 = *(const f32x4*)pp;
            f32x4 v1 = *(const f32x4*)(pp + 4);
            bf16x8 f;
            f[0]=f2bf(v0[0]); f[1]=f2bf(v0[1]); f[2]=f2bf(v0[2]); f[3]=f2bf(v0[3]);
            f[4]=f2bf(v1[0]); f[5]=f2bf(v1[1]); f[6]=f2bf(v1[2]); f[7]=f2bf(v1[3]);
            a1[kc] = f;
        }
    }

    // preload swizzled T rows: 4 rows x 32 B vector loads (32 VGPR)
    const unsigned short* T = ws16 + OFF_T/2;
    uint4 tra[4][2];
    #pragma unroll
    for (int r = 0; r < 4; r++) {
        int row = b*MTOK + idxS[wv*16 + q*4 + r];
        const uint4* tp = (const uint4*)(T + (size_t)row*HID + l*16);
        tra[r][0] = tp[0];
        tra[r][1] = tp[1];
    }

    const unsigned short* w2tG = ws16 + OFF_W2T/2;

    // identity B-frag for the transpose MFMA
    f16x4 ident;
    #pragma unroll
    for (int j = 0; j < 4; j++)
        ident[j] = (q*4 + j == l) ? (_Float16)1.0f : (_Float16)0.0f;

    const f32x4 zero4 = {0.f,0.f,0.f,0.f};
    f32x4 acc2 = zero4;

    #pragma unroll
    for (int nt = 0; nt < 16; nt++) {
        bf16x8 wf0 = __builtin_bit_cast(bf16x8, w1aS[nt*64 + lane]);
        bf16x8 wf1 = __builtin_bit_cast(bf16x8, w1aS[(16 + nt)*64 + lane]);
        f16x4 w2t = *(const f16x4*)(w2tG + (nt*64 + lane)*4);  // L2 hit
        f32x4 d1 = __builtin_amdgcn_mfma_f32_16x16x32_bf16(a1[0], wf0, zero4, 0, 0, 0);
        d1       = __builtin_amdgcn_mfma_f32_16x16x32_bf16(a1[1], wf1, d1,    0, 0, 0);
        f16x4 aT;
        #pragma unroll
        for (int r = 0; r < 4; r++) {
            unsigned dw = ((const unsigned*)&tra[r])[nt >> 1];
            float tval = (nt & 1) ? __uint_as_float(dw & 0xFFFF0000u)
                                  : __uint_as_float(dw << 16);
            float v = fmaxf(d1[r] + tval, 0.0f);
            aT[r] = (_Float16)v;
        }
        // transpose: lane -> h[vox=l][col=q*4+j]
        f32x4 ht = __builtin_amdgcn_mfma_f32_16x16x16f16(aT, ident, zero4, 0, 0, 0);
        f16x4 hb;
        hb[0]=(_Float16)ht[0]; hb[1]=(_Float16)ht[1];
        hb[2]=(_Float16)ht[2]; hb[3]=(_Float16)ht[3];
        acc2 = __builtin_amdgcn_mfma_f32_16x16x16f16(w2t, hb, acc2, 0, 0, 0);
    }

    // epilogue: lane l = voxel, rows q*4+r = output channel
    f32x4 bb = *(const f32x4*)(b2 + q*4);
    f32x4 o = acc2 + bb;
    *(f32x4*)(out + (size_t)(voxG + l)*OUTD + q*4) = o;
}

// ============================================================================
extern "C" void kernel_launch(void* const* d_in, const int* in_sizes, int n_in,
                              void* d_out, int out_size, void* d_ws, size_t ws_size,
                              hipStream_t stream)
{
    const float* patch  = (const float*)d_in[0];
    const float* vfeat  = (const float*)d_in[1];
    const float* coords = (const float*)d_in[2];
    const float* Km     = (const float*)d_in[3];
    const float* Rt     = (const float*)d_in[4];
    const float* W1     = (const float*)d_in[5];
    const float* b1     = (const float*)d_in[6];
    const float* W2     = (const float*)d_in[7];
    const float* b2     = (const float*)d_in[8];
    float* out          = (float*)d_out;
    unsigned short* ws16 = (unsigned short*)d_ws;

    const int prepBlocks = W1B_BLKS + W1A_BLKS + W2T_BLKS;   // 464
    prep_kernel<<<prepBlocks, 256, 0, stream>>>(W1, W2, ws16);
    t_gemm_kernel<<<T_BLKS, 256, 0, stream>>>(patch, ws16, b1, ws16);
    main_kernel<<<(BATCH*VOXPB)/64, 256, 0, stream>>>(vfeat, coords, Km, Rt,
                                                      ws16, b2, out);
}